// Round 1
// baseline (811.547 us; speedup 1.0000x reference)
//
#include <hip/hip_runtime.h>

#define N_NODES 8192
#define DEGREE 32
#define N_EDGES (N_NODES * DEGREE)
#define D_FEAT 256
#define F4 (D_FEAT / 4)   // float4 columns per row = 64

// ---------------------------------------------------------------------------
// Kernel 1: row-normalize edge weights.
// src = repeat(arange(N_NODES), DEGREE) by construction, so edges are grouped
// by row in blocks of 32. Reduce each 32-lane subgroup via shuffle.
// ---------------------------------------------------------------------------
__global__ __launch_bounds__(256) void normalize_kernel(
    const float* __restrict__ e, float* __restrict__ w) {
  int g = blockIdx.x * 256 + threadIdx.x;
  float v = e[g];
  float s = v;
  // butterfly reduce within 32-lane subgroups (rows are 32-aligned)
  for (int m = 1; m < 32; m <<= 1) s += __shfl_xor(s, m, 32);
  w[g] = v / s;
}

// ---------------------------------------------------------------------------
// Kernel 2: sparse SpMM  y = A @ x, optionally accumulating coef*y into out.
// One block = 4 rows. 64 lanes per row (one wave), float4 per lane.
// Edge lists (dst, w) staged into LDS; inner loop reads are wave-broadcast.
// MODE: 0 = y only, 1 = out = coef*acc (first tap, overwrites poison),
//       2 = out += coef*acc.
// ---------------------------------------------------------------------------
template <int MODE>
__global__ __launch_bounds__(256) void spmm_kernel(
    const int* __restrict__ dst, const float* __restrict__ w,
    const float* __restrict__ x, float* __restrict__ y,
    float* __restrict__ out, float coef) {
  __shared__ int   s_dst[4][DEGREE];
  __shared__ float s_w[4][DEGREE];

  const int tid = threadIdx.x;
  const int rlocal = tid >> 6;   // 0..3 : row within block (whole wave same row)
  const int f = tid & 63;        // float4 column index 0..63
  const int row_base = blockIdx.x * 4;

  if (tid < 4 * DEGREE) {
    int rl = tid >> 5, j = tid & 31;
    int eidx = (row_base + rl) * DEGREE + j;
    s_dst[rl][j] = dst[eidx] * F4;  // pre-scale to float4-row offset
    s_w[rl][j]   = w[eidx];
  }
  __syncthreads();

  const float4* __restrict__ x4 = (const float4*)x;
  float4 acc = make_float4(0.f, 0.f, 0.f, 0.f);

#pragma unroll
  for (int j = 0; j < DEGREE; ++j) {
    float  wj = s_w[rlocal][j];          // LDS broadcast (no conflict)
    float4 v  = x4[s_dst[rlocal][j] + f]; // 1 KB coalesced gather per wave
    acc.x += wj * v.x;
    acc.y += wj * v.y;
    acc.z += wj * v.z;
    acc.w += wj * v.w;
  }

  const int oidx = (row_base + rlocal) * F4 + f;
  ((float4*)y)[oidx] = acc;

  if (MODE == 1) {
    float4 r = make_float4(coef * acc.x, coef * acc.y, coef * acc.z, coef * acc.w);
    ((float4*)out)[oidx] = r;
  } else if (MODE == 2) {
    float4 r = ((float4*)out)[oidx];
    r.x += coef * acc.x;
    r.y += coef * acc.y;
    r.z += coef * acc.z;
    r.w += coef * acc.w;
    ((float4*)out)[oidx] = r;
  }
}

// ---------------------------------------------------------------------------
// Launch: normalize once, then 32 sparse applications, tapping powers of 2.
// result = a + a^2/1! + a^4/2! + a^8/3! + a^16/4! + a^32/5!, out = result @ h
// ---------------------------------------------------------------------------
extern "C" void kernel_launch(void* const* d_in, const int* in_sizes, int n_in,
                              void* d_out, int out_size, void* d_ws, size_t ws_size,
                              hipStream_t stream) {
  // inputs: src (int32, unused: structure is known), dst (int32), e (f32), h (f32)
  const int*   dst = (const int*)d_in[1];
  const float* e   = (const float*)d_in[2];
  const float* h   = (const float*)d_in[3];
  float* out = (float*)d_out;

  char* ws = (char*)d_ws;
  float* w    = (float*)ws;                         // 1 MB normalized weights
  float* buf0 = (float*)(ws + (size_t)(1 << 20));   // 8 MB
  float* buf1 = (float*)(ws + (size_t)(9 << 20));   // 8 MB

  normalize_kernel<<<N_EDGES / 256, 256, 0, stream>>>(e, w);

  const float* xin = h;
  float* bufs[2] = {buf0, buf1};
  int pb = 0;

  for (int k = 1; k <= 32; ++k) {
    float* y = bufs[pb];
    float coef;
    int mode;
    switch (k) {
      case 1:  coef = 1.f;          mode = 1; break;
      case 2:  coef = 1.f;          mode = 2; break;
      case 4:  coef = 1.f / 2.f;    mode = 2; break;
      case 8:  coef = 1.f / 6.f;    mode = 2; break;
      case 16: coef = 1.f / 24.f;   mode = 2; break;
      case 32: coef = 1.f / 120.f;  mode = 2; break;
      default: coef = 0.f;          mode = 0; break;
    }
    if (mode == 0)
      spmm_kernel<0><<<N_NODES / 4, 256, 0, stream>>>(dst, w, xin, y, out, coef);
    else if (mode == 1)
      spmm_kernel<1><<<N_NODES / 4, 256, 0, stream>>>(dst, w, xin, y, out, coef);
    else
      spmm_kernel<2><<<N_NODES / 4, 256, 0, stream>>>(dst, w, xin, y, out, coef);
    xin = y;
    pb ^= 1;
  }
}